// Round 6
// baseline (934.445 us; speedup 1.0000x reference)
//
#include <hip/hip_runtime.h>
#include <hip/hip_cooperative_groups.h>

namespace cg = cooperative_groups;

#define NZg  512
#define NXg  512
#define NT   1200
#define NSRC 4
#define NREC 512
#define DTC  0.001f
#define DHC  10.0f

#define TILE   32            // interior tile per block
#define KK     16            // substeps per batch (= halo width), even
#define EE     64            // extended tile = TILE + 2*KK
#define EEP    (EE + 2)      // +2 padding rows (zeroed once)
#define NBATCH 75            // NT / KK
#define NTH    512           // 8 waves
#define RBUFN  32            // receiver LDS buffer slots (fallback past this)

typedef unsigned long long u64;

// Relaxed agent-scope atomics: plain global_load/store with sc0|sc1
// (bypass L1 + non-coherent per-XCD L2; coherent at memory-side L3).
__device__ __forceinline__ u64 ld_agent(const u64* p) {
    return __hip_atomic_load(p, __ATOMIC_RELAXED, __HIP_MEMORY_SCOPE_AGENT);
}
__device__ __forceinline__ void st_agent(u64* p, u64 v) {
    __hip_atomic_store(p, v, __ATOMIC_RELAXED, __HIP_MEMORY_SCOPE_AGENT);
}
__device__ __forceinline__ int ld_flag(const int* p) {
    return __hip_atomic_load(p, __ATOMIC_RELAXED, __HIP_MEMORY_SCOPE_AGENT);
}
__device__ __forceinline__ u64 pack2(float a, float b) {
    union { float f[2]; u64 u; } c; c.f[0] = a; c.f[1] = b; return c.u;
}
__device__ __forceinline__ float2 unpack2(u64 v) {
    union { u64 u; float f[2]; } c; c.u = v; return make_float2(c.f[0], c.f[1]);
}

// Temporal-blocked FDTD, p2p neighbor flag sync, fence-free, 4x2 register
// patches. Latency-chain trimmed: LDS-buffered receiver traces (no global
// store ACK on the substep chain), multi-wave flag polling with LDS release
// (no post-spin barrier), ring-only tile reload (interior stays in regs).
__global__ __launch_bounds__(NTH, 1)
void wave_lt(const float* __restrict__ xsrc,   // (NSRC, NT)
             const float* __restrict__ vel,    // (NZ, NX)
             const int*   __restrict__ src_z,
             const int*   __restrict__ src_x,
             const int*   __restrict__ rec_z,
             const int*   __restrict__ rec_x,
             float*       __restrict__ out,    // (NT, NREC)
             u64*         __restrict__ slot0,  // (cur, prev) per cell
             u64*         __restrict__ slot1,
             int*         __restrict__ flags)  // (256)
{
    cg::grid_group grid = cg::this_grid();

    __shared__ float sA[EEP * EE];
    __shared__ float sB[EEP * EE];
    __shared__ float sx[NSRC * NT];
    __shared__ float rbuf[RBUFN * KK];
    __shared__ int   recl[NREC];
    __shared__ int   nrec_s;
    __shared__ int   sdone;            // released-batch epoch (monotone)

    const int tid  = threadIdx.x;
    const int lane = tid & 63;
    const int me   = blockIdx.x;
    const int bz   = me >> 4, bx = me & 15;
    const int oz   = bz * TILE - KK;
    const int ox   = bx * TILE - KK;
    const int pc   = tid & 15;       // patch column: cells 4pc .. 4pc+3
    const int pr   = tid >> 4;       // patch row: tile rows 2pr, 2pr+1
    const int lx   = 4 * pc;
    const int z0   = 2 * pr;         // top tile row of patch
    const int gx   = ox + lx;
    const int gz0  = oz + z0;
    const int gz1  = gz0 + 1;
    const bool inner = (pr >= 8 && pr < 24 && pc >= 4 && pc < 12);

    // Reset flag + LDS state (stale values survive between graph replays).
    if (tid == 0) { flags[me] = 0; nrec_s = 0; sdone = 0; }

    // Zero LDS padding rows (rows 0 and EEP-1 of both buffers) once.
    if (tid < 2 * EE) {
        const int r = (tid < EE) ? 0 : (EEP - 1);
        const int c = tid & (EE - 1);
        sA[r * EE + c] = 0.f;  sB[r * EE + c] = 0.f;
    }
    // Stage source traces in LDS.
    for (int i = tid; i < NSRC * NT; i += NTH) sx[i] = xsrc[i];
    __syncthreads();

    // Receiver list for this block's interior.
    for (int r = tid; r < NREC; r += NTH) {
        const int rz = rec_z[r], rx = rec_x[r];
        if (rz >= bz * TILE && rz < bz * TILE + TILE &&
            rx >= bx * TILE && rx < bx * TILE + TILE) {
            const int lzp = rz - oz + 1;          // padded row
            const int lxx = rx - ox;
            const int s = atomicAdd(&nrec_s, 1);
            recl[s] = (r << 16) | (lzp << 8) | lxx;
        }
    }

    // Per-cell coefficients (coef=0 out-of-domain pins those cells to 0)
    // and source bitmask: bit (c*4+s), cells 0..3 top row, 4..7 bottom.
    float4 c0 = make_float4(0.f, 0.f, 0.f, 0.f);
    float4 c1 = c0;
    unsigned int smask = 0;
    {
        int szr[NSRC], sxr[NSRC];
#pragma unroll
        for (int s = 0; s < NSRC; ++s) { szr[s] = src_z[s]; sxr[s] = src_x[s]; }
        float* cc0 = &c0.x;  float* cc1 = &c1.x;
#pragma unroll
        for (int k = 0; k < 4; ++k) {
            const int gxk = gx + k;
            const bool okx = (gxk >= 0 && gxk < NXg);
            if (okx && gz0 >= 0 && gz0 < NZg) {
                const float v = vel[gz0 * NXg + gxk];
                cc0[k] = (v * DTC) * (v * DTC) / (DHC * DHC);
#pragma unroll
                for (int s = 0; s < NSRC; ++s)
                    if (szr[s] == gz0 && sxr[s] == gxk) smask |= 1u << (k * 4 + s);
            }
            if (okx && gz1 >= 0 && gz1 < NZg) {
                const float v = vel[gz1 * NXg + gxk];
                cc1[k] = (v * DTC) * (v * DTC) / (DHC * DHC);
#pragma unroll
                for (int s = 0; s < NSRC; ++s)
                    if (szr[s] == gz1 && sxr[s] == gxk) smask |= 1u << ((4 + k) * 4 + s);
            }
        }
    }
    __syncthreads();
    const int nr    = nrec_s;
    const int myrec = (tid < nr) ? recl[tid] : 0;
    grid.sync();                 // flags reset everywhere; the ONLY grid sync

    float4 own0 = make_float4(0.f, 0.f, 0.f, 0.f), own1 = own0;
    float4 prv0 = own0, prv1 = own0;
    const int cb0 = (z0 + 1) * EE + lx;          // padded LDS index, top row
    const int cb1 = cb0 + EE;                    // bottom row

    // Per-LANE neighbor mapping (every wave polls all 8 flags in one load).
    bool havenb = false; int nbidx = 0;
    if (lane < 9 && lane != 4) {
        const int nz = bz + lane / 3 - 1, nx = bx + lane % 3 - 1;
        havenb = (nz >= 0 && nz < 16 && nx >= 0 && nx < 16);
        nbidx  = nz * 16 + nx;
    }

    // One leapfrog substep: read src_, write dst_, buffer receivers in LDS.
    auto STEP = [&](float* __restrict__ dst_, const float* __restrict__ src_,
                    int t, int jj) {
        const float4 U  = *(const float4*)&src_[cb0 - EE];
        const float4 D  = *(const float4*)&src_[cb1 + EE];
        const float  l0 = src_[cb0 - 1], r0v = src_[cb0 + 4];
        const float  l1 = src_[cb1 - 1], r1v = src_[cb1 + 4];

        float4 n0, n1;
        n0.x = 2.f * own0.x - prv0.x + c0.x * (U.x + own1.x + l0     + own0.y - 4.f * own0.x);
        n0.y = 2.f * own0.y - prv0.y + c0.y * (U.y + own1.y + own0.x + own0.z - 4.f * own0.y);
        n0.z = 2.f * own0.z - prv0.z + c0.z * (U.z + own1.z + own0.y + own0.w - 4.f * own0.z);
        n0.w = 2.f * own0.w - prv0.w + c0.w * (U.w + own1.w + own0.z + r0v    - 4.f * own0.w);
        n1.x = 2.f * own1.x - prv1.x + c1.x * (own0.x + D.x + l1     + own1.y - 4.f * own1.x);
        n1.y = 2.f * own1.y - prv1.y + c1.y * (own0.y + D.y + own1.x + own1.z - 4.f * own1.y);
        n1.z = 2.f * own1.z - prv1.z + c1.z * (own0.z + D.z + own1.y + own1.w - 4.f * own1.z);
        n1.w = 2.f * own1.w - prv1.w + c1.w * (own0.w + D.w + own1.z + r1v    - 4.f * own1.w);

        if (smask) {
            float* pn0 = &n0.x;  float* pn1 = &n1.x;
#pragma unroll
            for (int s = 0; s < NSRC; ++s) {
                const float amp = sx[s * NT + t];
#pragma unroll
                for (int k = 0; k < 4; ++k) {
                    if (smask & (1u << (k * 4 + s)))       pn0[k] += amp;
                    if (smask & (1u << ((4 + k) * 4 + s))) pn1[k] += amp;
                }
            }
        }

        *(float4*)&dst_[cb0] = n0;
        *(float4*)&dst_[cb1] = n1;
        prv0 = own0;  prv1 = own1;
        own0 = n0;    own1 = n1;
        __syncthreads();
        if (tid < nr) {
            const float v = dst_[((myrec >> 8) & 0xFF) * EE + (myrec & 0xFF)];
            if (tid < RBUFN) rbuf[tid * KK + jj] = v;
            else out[t * NREC + (myrec >> 16)] = v;   // overflow fallback
        }
    };

    for (int b = 0; b < NBATCH; ++b) {
        const u64* gin  = (b & 1) ? slot1 : slot0;
        u64*       gout = (b & 1) ? slot0 : slot1;

        // ---- wait: every wave polls all 8 flags; first releases via LDS ----
        if (b > 0) {
            bool rel = (__hip_atomic_load(&sdone, __ATOMIC_RELAXED,
                                          __HIP_MEMORY_SCOPE_WORKGROUP) >= b);
            while (!rel) {
                const bool ok = havenb ? (ld_flag(&flags[nbidx]) >= b) : true;
                if (__all(ok)) {
                    if (lane == 0)
                        __hip_atomic_store(&sdone, b, __ATOMIC_RELAXED,
                                           __HIP_MEMORY_SCOPE_WORKGROUP);
                    rel = true;
                } else {
                    __builtin_amdgcn_s_sleep(1);
                    rel = (__hip_atomic_load(&sdone, __ATOMIC_RELAXED,
                                             __HIP_MEMORY_SCOPE_WORKGROUP) >= b);
                }
            }
        }

        // ---- load ring into regs (interior regs already hold batch state) --
        if (!inner) {
            float* po0 = &own0.x;  float* pp0 = &prv0.x;
            float* po1 = &own1.x;  float* pp1 = &prv1.x;
#pragma unroll
            for (int k = 0; k < 4; ++k) {
                const int gxk = gx + k;
                const bool okx = (gxk >= 0 && gxk < NXg);
                if (b > 0 && okx && gz0 >= 0 && gz0 < NZg) {
                    const float2 v = unpack2(ld_agent(&gin[gz0 * NXg + gxk]));
                    po0[k] = v.x;  pp0[k] = v.y;
                } else { po0[k] = 0.f;  pp0[k] = 0.f; }
                if (b > 0 && okx && gz1 >= 0 && gz1 < NZg) {
                    const float2 v = unpack2(ld_agent(&gin[gz1 * NXg + gxk]));
                    po1[k] = v.x;  pp1[k] = v.y;
                } else { po1[k] = 0.f;  pp1[k] = 0.f; }
            }
        }
        *(float4*)&sB[cb0] = own0;
        *(float4*)&sB[cb1] = own1;
        __syncthreads();

        // ---- KK substeps, statically ping-ponged ----
        for (int j = 0; j < KK; j += 2) {
            STEP(sA, sB, b * KK + j,     j);
            STEP(sB, sA, b * KK + j + 1, j + 1);
        }

        // ---- flush buffered receiver traces (ACKs drain at publish bar) ----
        if (tid < nr && tid < RBUFN) {
            const int rid = myrec >> 16;
#pragma unroll
            for (int j = 0; j < KK; ++j)
                out[(b * KK + j) * NREC + rid] = rbuf[tid * KK + j];
        }

        // ---- write back 32x32 interior ----
        if (inner) {
            const float* po0 = &own0.x;  const float* pp0 = &prv0.x;
            const float* po1 = &own1.x;  const float* pp1 = &prv1.x;
#pragma unroll
            for (int k = 0; k < 4; ++k) {
                st_agent(&gout[gz0 * NXg + gx + k], pack2(po0[k], pp0[k]));
                st_agent(&gout[gz1 * NXg + gx + k], pack2(po1[k], pp1[k]));
            }
        }
        __syncthreads();         // every wave drains vmcnt before s_barrier
        if (tid == 0) {          // publish: data is globally visible already
            __hip_atomic_store(&flags[me], b + 1, __ATOMIC_RELAXED,
                               __HIP_MEMORY_SCOPE_AGENT);
        }
    }
}

extern "C" void kernel_launch(void* const* d_in, const int* in_sizes, int n_in,
                              void* d_out, int out_size, void* d_ws, size_t ws_size,
                              hipStream_t stream) {
    const float* xsrc  = (const float*)d_in[0];
    const float* vel   = (const float*)d_in[1];
    const int*   src_z = (const int*)  d_in[2];
    const int*   src_x = (const int*)  d_in[3];
    const int*   rec_z = (const int*)  d_in[4];
    const int*   rec_x = (const int*)  d_in[5];
    float*       out   = (float*)d_out;

    u64* slot0 = (u64*)d_ws;
    u64* slot1 = slot0 + NZg * NXg;
    int* flags = (int*)(slot1 + NZg * NXg);

    void* args[] = {(void*)&xsrc, (void*)&vel, (void*)&src_z, (void*)&src_x,
                    (void*)&rec_z, (void*)&rec_x, (void*)&out,
                    (void*)&slot0, (void*)&slot1, (void*)&flags};

    dim3 grid(256), block(NTH);
    hipLaunchCooperativeKernel((const void*)wave_lt, grid, block, args, 0, stream);
}